// Round 1
// baseline (1535.091 us; speedup 1.0000x reference)
//
#include <hip/hip_runtime.h>
#include <hip/hip_bf16.h>
#include <cstdint>

#define HID 64
#define NPG 100

// decoder chain-graph degree: in-edges into position p come from p-1,p-2,p+1,p+2 (valid ones), +1 self-loop
__device__ __forceinline__ float dinvdec(int p) {
    int d = (p >= 1) + (p >= 2) + (p <= NPG - 2) + (p <= NPG - 3);
    return rsqrtf((float)(d + 1));
}

// ---------------- CSR build ----------------

__global__ void zero_int_kernel(int* __restrict__ p, int n) {
    int i = blockIdx.x * 256 + threadIdx.x;
    if (i < n) p[i] = 0;
}

__global__ void count_kernel(const int* __restrict__ dst, int* __restrict__ cnt, int E) {
    int e = blockIdx.x * 256 + threadIdx.x;
    if (e < E) atomicAdd(&cnt[dst[e]], 1);
}

__global__ void dinv_kernel(const int* __restrict__ cnt, float* __restrict__ dinv, int N) {
    int i = blockIdx.x * 256 + threadIdx.x;
    if (i < N) dinv[i] = rsqrtf((float)cnt[i] + 1.0f);
}

// block scans 2048 ints (256 thr x 8)
__global__ __launch_bounds__(256) void scan1_kernel(const int* __restrict__ cnt,
                                                    int* __restrict__ row_ptr,
                                                    int* __restrict__ partials, int N) {
    __shared__ int sd[256];
    int tid = threadIdx.x;
    int base = blockIdx.x * 2048 + tid * 8;
    int v[8];
    int s = 0;
#pragma unroll
    for (int j = 0; j < 8; j++) {
        int i = base + j;
        int t = (i < N) ? cnt[i] : 0;
        v[j] = t; s += t;
    }
    sd[tid] = s;
    __syncthreads();
    for (int off = 1; off < 256; off <<= 1) {
        int t = (tid >= off) ? sd[tid - off] : 0;
        __syncthreads();
        sd[tid] += t;
        __syncthreads();
    }
    int run = sd[tid] - s;  // exclusive within block
#pragma unroll
    for (int j = 0; j < 8; j++) {
        int i = base + j;
        if (i < N) row_ptr[i] = run;
        run += v[j];
    }
    if (tid == 0) partials[blockIdx.x] = sd[255];
}

__global__ void scan2_kernel(int* __restrict__ partials, int nb) {
    __shared__ int sd[128];
    int tid = threadIdx.x;
    int v = (tid < nb) ? partials[tid] : 0;
    sd[tid] = v;
    __syncthreads();
    for (int off = 1; off < 128; off <<= 1) {
        int t = (tid >= off) ? sd[tid - off] : 0;
        __syncthreads();
        sd[tid] += t;
        __syncthreads();
    }
    if (tid < nb) partials[tid] = sd[tid] - v;
}

__global__ void scan3_kernel(int* __restrict__ row_ptr, const int* __restrict__ partials,
                             int N, int E) {
    int base = blockIdx.x * 2048 + threadIdx.x * 8;
    int add = partials[blockIdx.x];
#pragma unroll
    for (int j = 0; j < 8; j++) {
        int i = base + j;
        if (i < N) row_ptr[i] += add;
    }
    if (blockIdx.x == 0 && threadIdx.x == 0) row_ptr[N] = E;
}

__global__ void fill_kernel(const int* __restrict__ src, const int* __restrict__ dst,
                            const int* __restrict__ row_ptr, int* __restrict__ cursor,
                            int* __restrict__ csr_src, int E) {
    int e = blockIdx.x * 256 + threadIdx.x;
    if (e >= E) return;
    int d = dst[e];
    int pos = row_ptr[d] + atomicAdd(&cursor[d], 1);
    csr_src[pos] = src[e];
}

// ---------------- GEMM ----------------
// out[M,N] = A[M,K] @ W[K,N], epilogue: optional row scale (dinv array or decoder-pos dinv), optional bias.
// 256 threads; each computes 2 rows x 8 cols; RPB*N == 4096. A tile staged transposed in LDS (K-step 64).
template <int K, int N, int SCALE_MODE, bool BIAS>
__global__ __launch_bounds__(256) void gemm_kernel(const float* __restrict__ A,
                                                   const float* __restrict__ W,
                                                   const float* __restrict__ bias,
                                                   const float* __restrict__ rowscale,
                                                   float* __restrict__ out, int M) {
    constexpr int RPB = 4096 / N;   // 64 (N=64) or 32 (N=128)
    constexpr int KS = 64;
    __shared__ float At[KS][RPB];
    __shared__ float Ws[K][N];
    const int tid = threadIdx.x;
    const int m0 = blockIdx.x * RPB;

    for (int idx = tid; idx < K * N / 4; idx += 256)
        ((float4*)&Ws[0][0])[idx] = ((const float4*)W)[idx];

    constexpr int RG = RPB / 2;
    const int trow = tid % RG, tcg = tid / RG;
    const int r0 = 2 * trow, c0 = 8 * tcg;

    float acc[2][8] = {};

    for (int kh = 0; kh < K; kh += KS) {
        __syncthreads();  // protect At (and first-iter Ws ordering is covered by the next sync)
        for (int idx = tid; idx < RPB * (KS / 4); idx += 256) {
            int r = idx / (KS / 4), c4 = idx % (KS / 4);
            float4 v = ((const float4*)(A + (size_t)(m0 + r) * K + kh))[c4];
            At[c4 * 4 + 0][r] = v.x;
            At[c4 * 4 + 1][r] = v.y;
            At[c4 * 4 + 2][r] = v.z;
            At[c4 * 4 + 3][r] = v.w;
        }
        __syncthreads();
#pragma unroll 4
        for (int kk = 0; kk < KS; kk++) {
            const float4* wr = (const float4*)&Ws[kh + kk][c0];
            float4 wa = wr[0], wb = wr[1];
            float a0 = At[kk][r0], a1 = At[kk][r0 + 1];
            float w[8] = {wa.x, wa.y, wa.z, wa.w, wb.x, wb.y, wb.z, wb.w};
#pragma unroll
            for (int j = 0; j < 8; j++) {
                acc[0][j] += a0 * w[j];
                acc[1][j] += a1 * w[j];
            }
        }
    }

#pragma unroll
    for (int i = 0; i < 2; i++) {
        int grow = m0 + r0 + i;
        float scale = 1.0f;
        if (SCALE_MODE == 1) scale = rowscale[grow];
        if (SCALE_MODE == 2) scale = dinvdec(grow % NPG);
        float4 o0, o1;
        o0.x = acc[i][0] * scale; o0.y = acc[i][1] * scale;
        o0.z = acc[i][2] * scale; o0.w = acc[i][3] * scale;
        o1.x = acc[i][4] * scale; o1.y = acc[i][5] * scale;
        o1.z = acc[i][6] * scale; o1.w = acc[i][7] * scale;
        if (BIAS) {
            float4 b0 = ((const float4*)bias)[c0 / 4];
            float4 b1 = ((const float4*)bias)[c0 / 4 + 1];
            o0.x += b0.x; o0.y += b0.y; o0.z += b0.z; o0.w += b0.w;
            o1.x += b1.x; o1.y += b1.y; o1.z += b1.z; o1.w += b1.w;
        }
        float* orow = out + (size_t)grow * N + c0;
        ((float4*)orow)[0] = o0;
        ((float4*)orow)[1] = o1;
    }
}

// ---------------- encoder aggregation (gather over CSR) ----------------
// g already holds (x@W)*dinv[row]. out[i] = dinv[i]*(g[i] + sum_{e in(i)} g[src]) + b, optional relu.
__global__ __launch_bounds__(256) void agg_kernel(const float* __restrict__ g,
                                                  const int* __restrict__ row_ptr,
                                                  const int* __restrict__ csr_src,
                                                  const float* __restrict__ dinv,
                                                  const float* __restrict__ bias,
                                                  float* __restrict__ out, int N, int do_relu) {
    int wid = (blockIdx.x * 256 + threadIdx.x) >> 6;
    int lane = threadIdx.x & 63;
    if (wid >= N) return;
    float acc = g[(size_t)wid * HID + lane];
    int s = row_ptr[wid], e = row_ptr[wid + 1];
    for (int j = s; j < e; j++) {
        int sr = csr_src[j];
        acc += g[(size_t)sr * HID + lane];
    }
    float v = dinv[wid] * acc + bias[lane];
    if (do_relu) v = fmaxf(v, 0.0f);
    out[(size_t)wid * HID + lane] = v;
}

// ---------------- pooling: mean over each graph's 100 rows ----------------
__global__ void pool_kernel(const float* __restrict__ h, float* __restrict__ emb, int NG) {
    int wid = (blockIdx.x * 256 + threadIdx.x) >> 6;
    int lane = threadIdx.x & 63;
    if (wid >= NG) return;
    const float* base = h + (size_t)wid * NPG * HID + lane;
    float acc = 0.0f;
    for (int i = 0; i < NPG; i++) acc += base[i * HID];
    emb[wid * HID + lane] = acc * (1.0f / NPG);
}

// ---------------- decoder init: t = (emb@Wt + bt) @ W1, one wave per graph ----------------
__global__ void decinit_kernel(const float* __restrict__ emb, const float* __restrict__ Wt,
                               const float* __restrict__ bt, const float* __restrict__ W1,
                               float* __restrict__ t, int NG) {
    int wid = (blockIdx.x * 256 + threadIdx.x) >> 6;
    int lane = threadIdx.x & 63;
    if (wid >= NG) return;
    float e = emb[wid * HID + lane];
    float acc = bt[lane];
    for (int k = 0; k < HID; k++) acc += __shfl(e, k) * Wt[k * HID + lane];
    float tv = 0.0f;
    for (int k = 0; k < HID; k++) tv += __shfl(acc, k) * W1[k * HID + lane];
    t[wid * HID + lane] = tv;
}

// ---------------- decoder layer 1: z1[i] = relu(t[graph]*s[pos] + b1), float4 per thread ----------------
__global__ void z1_kernel(const float* __restrict__ t, const float* __restrict__ b1,
                          float* __restrict__ out, int N) {
    int i4 = blockIdx.x * 256 + threadIdx.x;
    if (i4 >= N * (HID / 4)) return;
    int row = i4 >> 4, c4 = i4 & 15;
    int gph = row / NPG;
    int p = row - gph * NPG;
    float dp = dinvdec(p);
    float qs = dp;
    if (p >= 1) qs += dinvdec(p - 1);
    if (p >= 2) qs += dinvdec(p - 2);
    if (p <= NPG - 2) qs += dinvdec(p + 1);
    if (p <= NPG - 3) qs += dinvdec(p + 2);
    float s = dp * qs;
    float4 tv = ((const float4*)t)[gph * (HID / 4) + c4];
    float4 bv = ((const float4*)b1)[c4];
    float4 o;
    o.x = fmaxf(s * tv.x + bv.x, 0.0f);
    o.y = fmaxf(s * tv.y + bv.y, 0.0f);
    o.z = fmaxf(s * tv.z + bv.z, 0.0f);
    o.w = fmaxf(s * tv.w + bv.w, 0.0f);
    ((float4*)out)[i4] = o;
}

// ---------------- decoder stencil layers (one block per graph) ----------------
// g holds (z@W)*dinvdec[pos]. out[i] = relu(dinvdec(p)*(g[i]+g[i-1]+g[i-2]+g[i+1]+g[i+2]) + b)
__global__ __launch_bounds__(256) void stencil_kernel(const float* __restrict__ g,
                                                      const float* __restrict__ bias,
                                                      float* __restrict__ out, int NG) {
    __shared__ float gs[NPG * HID];
    int gph = blockIdx.x;
    const float4* src = (const float4*)(g + (size_t)gph * NPG * HID);
    for (int idx = threadIdx.x; idx < NPG * HID / 4; idx += 256)
        ((float4*)gs)[idx] = src[idx];
    __syncthreads();
    int c = threadIdx.x & 63;
    for (int p = threadIdx.x >> 6; p < NPG; p += 4) {
        float acc = gs[p * HID + c];
        if (p >= 1) acc += gs[(p - 1) * HID + c];
        if (p >= 2) acc += gs[(p - 2) * HID + c];
        if (p <= NPG - 2) acc += gs[(p + 1) * HID + c];
        if (p <= NPG - 3) acc += gs[(p + 2) * HID + c];
        float v = dinvdec(p) * acc + bias[c];
        v = fmaxf(v, 0.0f);
        out[(size_t)(gph * NPG + p) * HID + c] = v;
    }
}

// ---------------- launch ----------------

extern "C" void kernel_launch(void* const* d_in, const int* in_sizes, int n_in,
                              void* d_out, int out_size, void* d_ws, size_t ws_size,
                              hipStream_t stream) {
    const float* x      = (const float*)d_in[0];
    const int*   edge   = (const int*)d_in[1];
    const float* enc_W1 = (const float*)d_in[3];
    const float* enc_b1 = (const float*)d_in[4];
    const float* enc_W2 = (const float*)d_in[5];
    const float* enc_b2 = (const float*)d_in[6];
    const float* enc_W3 = (const float*)d_in[7];
    const float* enc_b3 = (const float*)d_in[8];
    const float* dec_Wt = (const float*)d_in[9];
    const float* dec_bt = (const float*)d_in[10];
    const float* dec_W1 = (const float*)d_in[11];
    const float* dec_b1 = (const float*)d_in[12];
    const float* dec_W2 = (const float*)d_in[13];
    const float* dec_b2 = (const float*)d_in[14];
    const float* dec_W3 = (const float*)d_in[15];
    const float* dec_b3 = (const float*)d_in[16];
    const float* out_W  = (const float*)d_in[17];
    const float* out_b  = (const float*)d_in[18];

    const int N  = in_sizes[0] / 128;  // 200000
    const int E  = in_sizes[1] / 2;    // 3200000
    const int NG = N / NPG;            // 2000
    const int* esrc = edge;
    const int* edst = edge + E;

    // workspace carve (256B aligned)
    char* w = (char*)d_ws;
    auto alloc = [&](size_t bytes) -> void* {
        void* p = (void*)w;
        w += (bytes + 255) & ~(size_t)255;
        return p;
    };
    float* bufA    = (float*)alloc((size_t)N * HID * 4);
    int*   csr     = (int*)alloc((size_t)E * 4);
    int*   row_ptr = (int*)alloc((size_t)(N + 1) * 4);
    int*   cnt     = (int*)alloc((size_t)N * 4);
    int*   cursor  = (int*)alloc((size_t)N * 4);
    float* dinv    = (float*)alloc((size_t)N * 4);
    int*   partials= (int*)alloc(1024);
    float* emb     = (float*)alloc((size_t)NG * HID * 4);
    float* tbuf    = (float*)alloc((size_t)NG * HID * 4);

    float* B1 = (float*)d_out;                    // first 51.2 MB of d_out as scratch
    float* B2 = (float*)d_out + (size_t)N * HID;  // second 51.2 MB

    const int NB = (N + 2047) / 2048;

    // CSR build
    zero_int_kernel<<<(N + 255) / 256, 256, 0, stream>>>(cnt, N);
    zero_int_kernel<<<(N + 255) / 256, 256, 0, stream>>>(cursor, N);
    count_kernel<<<(E + 255) / 256, 256, 0, stream>>>(edst, cnt, E);
    dinv_kernel<<<(N + 255) / 256, 256, 0, stream>>>(cnt, dinv, N);
    scan1_kernel<<<NB, 256, 0, stream>>>(cnt, row_ptr, partials, N);
    scan2_kernel<<<1, 128, 0, stream>>>(partials, NB);
    scan3_kernel<<<NB, 256, 0, stream>>>(row_ptr, partials, N, E);
    fill_kernel<<<(E + 255) / 256, 256, 0, stream>>>(esrc, edst, row_ptr, cursor, csr, E);

    // encoder
    gemm_kernel<128, 64, 1, false><<<N / 64, 256, 0, stream>>>(x, enc_W1, nullptr, dinv, bufA, N);
    agg_kernel<<<(N + 3) / 4, 256, 0, stream>>>(bufA, row_ptr, csr, dinv, enc_b1, B1, N, 1);
    gemm_kernel<64, 64, 1, false><<<N / 64, 256, 0, stream>>>(B1, enc_W2, nullptr, dinv, bufA, N);
    agg_kernel<<<(N + 3) / 4, 256, 0, stream>>>(bufA, row_ptr, csr, dinv, enc_b2, B1, N, 1);
    gemm_kernel<64, 64, 1, false><<<N / 64, 256, 0, stream>>>(B1, enc_W3, nullptr, dinv, bufA, N);
    agg_kernel<<<(N + 3) / 4, 256, 0, stream>>>(bufA, row_ptr, csr, dinv, enc_b3, B1, N, 0);

    // pooling + decoder head
    pool_kernel<<<(NG * 64 + 255) / 256, 256, 0, stream>>>(B1, emb, NG);
    decinit_kernel<<<(NG * 64 + 255) / 256, 256, 0, stream>>>(emb, dec_Wt, dec_bt, dec_W1, tbuf, NG);
    z1_kernel<<<(N * 16 + 255) / 256, 256, 0, stream>>>(tbuf, dec_b1, B1, N);

    // decoder stencil layers
    gemm_kernel<64, 64, 2, false><<<N / 64, 256, 0, stream>>>(B1, dec_W2, nullptr, nullptr, bufA, N);
    stencil_kernel<<<NG, 256, 0, stream>>>(bufA, dec_b2, B1, NG);
    gemm_kernel<64, 64, 2, false><<<N / 64, 256, 0, stream>>>(B1, dec_W3, nullptr, nullptr, B2, N);
    stencil_kernel<<<NG, 256, 0, stream>>>(B2, dec_b3, bufA, NG);

    // output projection (reads ws bufA, overwrites all of d_out)
    gemm_kernel<64, 128, 0, true><<<N / 32, 256, 0, stream>>>(bufA, out_W, out_b, nullptr,
                                                              (float*)d_out, N);
}

// Round 2
// 1041.430 us; speedup vs baseline: 1.4740x; 1.4740x over previous
//
#include <hip/hip_runtime.h>
#include <hip/hip_bf16.h>
#include <cstdint>

#define HID 64
#define NPG 100

// decoder chain-graph degree: in-edges into position p come from p-1,p-2,p+1,p+2 (valid ones), +1 self-loop
__device__ __forceinline__ float dinvdec(int p) {
    int d = (p >= 1) + (p >= 2) + (p <= NPG - 2) + (p <= NPG - 3);
    return rsqrtf((float)(d + 1));
}

// ---------------- CSR build ----------------

__global__ void zero_int_kernel(int* __restrict__ p, int n) {
    int i = blockIdx.x * 256 + threadIdx.x;
    if (i < n) p[i] = 0;
}

__global__ void count_kernel(const int* __restrict__ dst, int* __restrict__ cnt, int E) {
    int e = blockIdx.x * 256 + threadIdx.x;
    if (e < E) atomicAdd(&cnt[dst[e]], 1);
}

__global__ void dinv_kernel(const int* __restrict__ cnt, float* __restrict__ dinv, int N) {
    int i = blockIdx.x * 256 + threadIdx.x;
    if (i < N) dinv[i] = rsqrtf((float)cnt[i] + 1.0f);
}

// block scans 2048 ints (256 thr x 8)
__global__ __launch_bounds__(256) void scan1_kernel(const int* __restrict__ cnt,
                                                    int* __restrict__ row_ptr,
                                                    int* __restrict__ partials, int N) {
    __shared__ int sd[256];
    int tid = threadIdx.x;
    int base = blockIdx.x * 2048 + tid * 8;
    int v[8];
    int s = 0;
#pragma unroll
    for (int j = 0; j < 8; j++) {
        int i = base + j;
        int t = (i < N) ? cnt[i] : 0;
        v[j] = t; s += t;
    }
    sd[tid] = s;
    __syncthreads();
    for (int off = 1; off < 256; off <<= 1) {
        int t = (tid >= off) ? sd[tid - off] : 0;
        __syncthreads();
        sd[tid] += t;
        __syncthreads();
    }
    int run = sd[tid] - s;  // exclusive within block
#pragma unroll
    for (int j = 0; j < 8; j++) {
        int i = base + j;
        if (i < N) row_ptr[i] = run;
        run += v[j];
    }
    if (tid == 0) partials[blockIdx.x] = sd[255];
}

__global__ void scan2_kernel(int* __restrict__ partials, int nb) {
    __shared__ int sd[128];
    int tid = threadIdx.x;
    int v = (tid < nb) ? partials[tid] : 0;
    sd[tid] = v;
    __syncthreads();
    for (int off = 1; off < 128; off <<= 1) {
        int t = (tid >= off) ? sd[tid - off] : 0;
        __syncthreads();
        sd[tid] += t;
        __syncthreads();
    }
    if (tid < nb) partials[tid] = sd[tid] - v;
}

__global__ void scan3_kernel(int* __restrict__ row_ptr, const int* __restrict__ partials,
                             int N, int E) {
    int base = blockIdx.x * 2048 + threadIdx.x * 8;
    int add = partials[blockIdx.x];
#pragma unroll
    for (int j = 0; j < 8; j++) {
        int i = base + j;
        if (i < N) row_ptr[i] += add;
    }
    if (blockIdx.x == 0 && threadIdx.x == 0) row_ptr[N] = E;
}

__global__ void fill_kernel(const int* __restrict__ src, const int* __restrict__ dst,
                            const int* __restrict__ row_ptr, int* __restrict__ cursor,
                            int* __restrict__ csr_src, int E) {
    int e = blockIdx.x * 256 + threadIdx.x;
    if (e >= E) return;
    int d = dst[e];
    int pos = row_ptr[d] + atomicAdd(&cursor[d], 1);
    csr_src[pos] = src[e];
}

// ---------------- GEMM ----------------
// out[M,N] = A[M,K] @ W[K,N], epilogue: optional row scale (dinv array or decoder-pos dinv), optional bias.
// 256 threads; each computes 2 rows x 8 cols; RPB*N == 4096. A tile staged transposed in LDS (K-step 64).
template <int K, int N, int SCALE_MODE, bool BIAS>
__global__ __launch_bounds__(256) void gemm_kernel(const float* __restrict__ A,
                                                   const float* __restrict__ W,
                                                   const float* __restrict__ bias,
                                                   const float* __restrict__ rowscale,
                                                   float* __restrict__ out, int M) {
    constexpr int RPB = 4096 / N;   // 64 (N=64) or 32 (N=128)
    constexpr int KS = 64;
    __shared__ float At[KS][RPB];
    __shared__ float Ws[K][N];
    const int tid = threadIdx.x;
    const int m0 = blockIdx.x * RPB;

    for (int idx = tid; idx < K * N / 4; idx += 256)
        ((float4*)&Ws[0][0])[idx] = ((const float4*)W)[idx];

    constexpr int RG = RPB / 2;
    const int trow = tid % RG, tcg = tid / RG;
    const int r0 = 2 * trow, c0 = 8 * tcg;

    float acc[2][8] = {};

    for (int kh = 0; kh < K; kh += KS) {
        __syncthreads();  // protect At (and first-iter Ws ordering is covered by the next sync)
        for (int idx = tid; idx < RPB * (KS / 4); idx += 256) {
            int r = idx / (KS / 4), c4 = idx % (KS / 4);
            float4 v = ((const float4*)(A + (size_t)(m0 + r) * K + kh))[c4];
            At[c4 * 4 + 0][r] = v.x;
            At[c4 * 4 + 1][r] = v.y;
            At[c4 * 4 + 2][r] = v.z;
            At[c4 * 4 + 3][r] = v.w;
        }
        __syncthreads();
#pragma unroll 4
        for (int kk = 0; kk < KS; kk++) {
            const float4* wr = (const float4*)&Ws[kh + kk][c0];
            float4 wa = wr[0], wb = wr[1];
            float a0 = At[kk][r0], a1 = At[kk][r0 + 1];
            float w[8] = {wa.x, wa.y, wa.z, wa.w, wb.x, wb.y, wb.z, wb.w};
#pragma unroll
            for (int j = 0; j < 8; j++) {
                acc[0][j] += a0 * w[j];
                acc[1][j] += a1 * w[j];
            }
        }
    }

#pragma unroll
    for (int i = 0; i < 2; i++) {
        int grow = m0 + r0 + i;
        float scale = 1.0f;
        if (SCALE_MODE == 1) scale = rowscale[grow];
        if (SCALE_MODE == 2) scale = dinvdec(grow % NPG);
        float4 o0, o1;
        o0.x = acc[i][0] * scale; o0.y = acc[i][1] * scale;
        o0.z = acc[i][2] * scale; o0.w = acc[i][3] * scale;
        o1.x = acc[i][4] * scale; o1.y = acc[i][5] * scale;
        o1.z = acc[i][6] * scale; o1.w = acc[i][7] * scale;
        if (BIAS) {
            float4 b0 = ((const float4*)bias)[c0 / 4];
            float4 b1 = ((const float4*)bias)[c0 / 4 + 1];
            o0.x += b0.x; o0.y += b0.y; o0.z += b0.z; o0.w += b0.w;
            o1.x += b1.x; o1.y += b1.y; o1.z += b1.z; o1.w += b1.w;
        }
        float* orow = out + (size_t)grow * N + c0;
        ((float4*)orow)[0] = o0;
        ((float4*)orow)[1] = o1;
    }
}

// ---------------- encoder aggregation (gather over CSR) ----------------
// g already holds (x@W)*dinv[row]. out[i] = dinv[i]*(g[i] + sum_{e in(i)} g[src]) + b, optional relu.
// 16 lanes per row (float4/lane = 256B per gather), 16 rows per 256-thread block.
// Edge loop unrolled x8: 8 independent index loads then 8 independent 256B gathers in flight.
__global__ __launch_bounds__(256) void agg_kernel(const float* __restrict__ g,
                                                  const int* __restrict__ row_ptr,
                                                  const int* __restrict__ csr_src,
                                                  const float* __restrict__ dinv,
                                                  const float* __restrict__ bias,
                                                  float* __restrict__ out, int N, int do_relu) {
    const int tid = threadIdx.x;
    const int sub = tid >> 4;        // 0..15: row within block
    const int lg = tid & 15;         // column group (float4)
    const int row = blockIdx.x * 16 + sub;
    if (row >= N) return;

    const float4* g4 = (const float4*)g;
    float4 acc = g4[(size_t)row * 16 + lg];

    const int s = row_ptr[row];
    const int e = row_ptr[row + 1];
    int j = s;

#define ACC4(vv) do { acc.x += vv.x; acc.y += vv.y; acc.z += vv.z; acc.w += vv.w; } while (0)

    for (; j + 8 <= e; j += 8) {
        int i0 = csr_src[j + 0], i1 = csr_src[j + 1], i2 = csr_src[j + 2], i3 = csr_src[j + 3];
        int i4 = csr_src[j + 4], i5 = csr_src[j + 5], i6 = csr_src[j + 6], i7 = csr_src[j + 7];
        float4 v0 = g4[(size_t)i0 * 16 + lg];
        float4 v1 = g4[(size_t)i1 * 16 + lg];
        float4 v2 = g4[(size_t)i2 * 16 + lg];
        float4 v3 = g4[(size_t)i3 * 16 + lg];
        float4 v4 = g4[(size_t)i4 * 16 + lg];
        float4 v5 = g4[(size_t)i5 * 16 + lg];
        float4 v6 = g4[(size_t)i6 * 16 + lg];
        float4 v7 = g4[(size_t)i7 * 16 + lg];
        ACC4(v0); ACC4(v1); ACC4(v2); ACC4(v3);
        ACC4(v4); ACC4(v5); ACC4(v6); ACC4(v7);
    }
    for (; j + 2 <= e; j += 2) {
        int i0 = csr_src[j + 0], i1 = csr_src[j + 1];
        float4 v0 = g4[(size_t)i0 * 16 + lg];
        float4 v1 = g4[(size_t)i1 * 16 + lg];
        ACC4(v0); ACC4(v1);
    }
    if (j < e) {
        int i0 = csr_src[j];
        float4 v0 = g4[(size_t)i0 * 16 + lg];
        ACC4(v0);
    }
#undef ACC4

    const float d = dinv[row];
    float4 bv = ((const float4*)bias)[lg];
    float4 o;
    o.x = d * acc.x + bv.x;
    o.y = d * acc.y + bv.y;
    o.z = d * acc.z + bv.z;
    o.w = d * acc.w + bv.w;
    if (do_relu) {
        o.x = fmaxf(o.x, 0.0f); o.y = fmaxf(o.y, 0.0f);
        o.z = fmaxf(o.z, 0.0f); o.w = fmaxf(o.w, 0.0f);
    }
    ((float4*)out)[(size_t)row * 16 + lg] = o;
}

// ---------------- pooling: mean over each graph's 100 rows ----------------
__global__ void pool_kernel(const float* __restrict__ h, float* __restrict__ emb, int NG) {
    int wid = (blockIdx.x * 256 + threadIdx.x) >> 6;
    int lane = threadIdx.x & 63;
    if (wid >= NG) return;
    const float* base = h + (size_t)wid * NPG * HID + lane;
    float acc = 0.0f;
    for (int i = 0; i < NPG; i++) acc += base[i * HID];
    emb[wid * HID + lane] = acc * (1.0f / NPG);
}

// ---------------- decoder init: t = (emb@Wt + bt) @ W1, one wave per graph ----------------
__global__ void decinit_kernel(const float* __restrict__ emb, const float* __restrict__ Wt,
                               const float* __restrict__ bt, const float* __restrict__ W1,
                               float* __restrict__ t, int NG) {
    int wid = (blockIdx.x * 256 + threadIdx.x) >> 6;
    int lane = threadIdx.x & 63;
    if (wid >= NG) return;
    float e = emb[wid * HID + lane];
    float acc = bt[lane];
    for (int k = 0; k < HID; k++) acc += __shfl(e, k) * Wt[k * HID + lane];
    float tv = 0.0f;
    for (int k = 0; k < HID; k++) tv += __shfl(acc, k) * W1[k * HID + lane];
    t[wid * HID + lane] = tv;
}

// ---------------- decoder layer 1: z1[i] = relu(t[graph]*s[pos] + b1), float4 per thread ----------------
__global__ void z1_kernel(const float* __restrict__ t, const float* __restrict__ b1,
                          float* __restrict__ out, int N) {
    int i4 = blockIdx.x * 256 + threadIdx.x;
    if (i4 >= N * (HID / 4)) return;
    int row = i4 >> 4, c4 = i4 & 15;
    int gph = row / NPG;
    int p = row - gph * NPG;
    float dp = dinvdec(p);
    float qs = dp;
    if (p >= 1) qs += dinvdec(p - 1);
    if (p >= 2) qs += dinvdec(p - 2);
    if (p <= NPG - 2) qs += dinvdec(p + 1);
    if (p <= NPG - 3) qs += dinvdec(p + 2);
    float s = dp * qs;
    float4 tv = ((const float4*)t)[gph * (HID / 4) + c4];
    float4 bv = ((const float4*)b1)[c4];
    float4 o;
    o.x = fmaxf(s * tv.x + bv.x, 0.0f);
    o.y = fmaxf(s * tv.y + bv.y, 0.0f);
    o.z = fmaxf(s * tv.z + bv.z, 0.0f);
    o.w = fmaxf(s * tv.w + bv.w, 0.0f);
    ((float4*)out)[i4] = o;
}

// ---------------- decoder stencil layers (one block per graph) ----------------
// g holds (z@W)*dinvdec[pos]. out[i] = relu(dinvdec(p)*(g[i]+g[i-1]+g[i-2]+g[i+1]+g[i+2]) + b)
__global__ __launch_bounds__(256) void stencil_kernel(const float* __restrict__ g,
                                                      const float* __restrict__ bias,
                                                      float* __restrict__ out, int NG) {
    __shared__ float gs[NPG * HID];
    int gph = blockIdx.x;
    const float4* src = (const float4*)(g + (size_t)gph * NPG * HID);
    for (int idx = threadIdx.x; idx < NPG * HID / 4; idx += 256)
        ((float4*)gs)[idx] = src[idx];
    __syncthreads();
    int c = threadIdx.x & 63;
    for (int p = threadIdx.x >> 6; p < NPG; p += 4) {
        float acc = gs[p * HID + c];
        if (p >= 1) acc += gs[(p - 1) * HID + c];
        if (p >= 2) acc += gs[(p - 2) * HID + c];
        if (p <= NPG - 2) acc += gs[(p + 1) * HID + c];
        if (p <= NPG - 3) acc += gs[(p + 2) * HID + c];
        float v = dinvdec(p) * acc + bias[c];
        v = fmaxf(v, 0.0f);
        out[(size_t)(gph * NPG + p) * HID + c] = v;
    }
}

// ---------------- launch ----------------

extern "C" void kernel_launch(void* const* d_in, const int* in_sizes, int n_in,
                              void* d_out, int out_size, void* d_ws, size_t ws_size,
                              hipStream_t stream) {
    const float* x      = (const float*)d_in[0];
    const int*   edge   = (const int*)d_in[1];
    const float* enc_W1 = (const float*)d_in[3];
    const float* enc_b1 = (const float*)d_in[4];
    const float* enc_W2 = (const float*)d_in[5];
    const float* enc_b2 = (const float*)d_in[6];
    const float* enc_W3 = (const float*)d_in[7];
    const float* enc_b3 = (const float*)d_in[8];
    const float* dec_Wt = (const float*)d_in[9];
    const float* dec_bt = (const float*)d_in[10];
    const float* dec_W1 = (const float*)d_in[11];
    const float* dec_b1 = (const float*)d_in[12];
    const float* dec_W2 = (const float*)d_in[13];
    const float* dec_b2 = (const float*)d_in[14];
    const float* dec_W3 = (const float*)d_in[15];
    const float* dec_b3 = (const float*)d_in[16];
    const float* out_W  = (const float*)d_in[17];
    const float* out_b  = (const float*)d_in[18];

    const int N  = in_sizes[0] / 128;  // 200000
    const int E  = in_sizes[1] / 2;    // 3200000
    const int NG = N / NPG;            // 2000
    const int* esrc = edge;
    const int* edst = edge + E;

    // workspace carve (256B aligned)
    char* w = (char*)d_ws;
    auto alloc = [&](size_t bytes) -> void* {
        void* p = (void*)w;
        w += (bytes + 255) & ~(size_t)255;
        return p;
    };
    float* bufA    = (float*)alloc((size_t)N * HID * 4);
    int*   csr     = (int*)alloc((size_t)E * 4);
    int*   row_ptr = (int*)alloc((size_t)(N + 1) * 4);
    int*   cnt     = (int*)alloc((size_t)N * 4);
    int*   cursor  = (int*)alloc((size_t)N * 4);
    float* dinv    = (float*)alloc((size_t)N * 4);
    int*   partials= (int*)alloc(1024);
    float* emb     = (float*)alloc((size_t)NG * HID * 4);
    float* tbuf    = (float*)alloc((size_t)NG * HID * 4);

    float* B1 = (float*)d_out;                    // first 51.2 MB of d_out as scratch
    float* B2 = (float*)d_out + (size_t)N * HID;  // second 51.2 MB

    const int NB = (N + 2047) / 2048;

    // CSR build
    zero_int_kernel<<<(N + 255) / 256, 256, 0, stream>>>(cnt, N);
    zero_int_kernel<<<(N + 255) / 256, 256, 0, stream>>>(cursor, N);
    count_kernel<<<(E + 255) / 256, 256, 0, stream>>>(edst, cnt, E);
    dinv_kernel<<<(N + 255) / 256, 256, 0, stream>>>(cnt, dinv, N);
    scan1_kernel<<<NB, 256, 0, stream>>>(cnt, row_ptr, partials, N);
    scan2_kernel<<<1, 128, 0, stream>>>(partials, NB);
    scan3_kernel<<<NB, 256, 0, stream>>>(row_ptr, partials, N, E);
    fill_kernel<<<(E + 255) / 256, 256, 0, stream>>>(esrc, edst, row_ptr, cursor, csr, E);

    // encoder
    gemm_kernel<128, 64, 1, false><<<N / 64, 256, 0, stream>>>(x, enc_W1, nullptr, dinv, bufA, N);
    agg_kernel<<<(N + 15) / 16, 256, 0, stream>>>(bufA, row_ptr, csr, dinv, enc_b1, B1, N, 1);
    gemm_kernel<64, 64, 1, false><<<N / 64, 256, 0, stream>>>(B1, enc_W2, nullptr, dinv, bufA, N);
    agg_kernel<<<(N + 15) / 16, 256, 0, stream>>>(bufA, row_ptr, csr, dinv, enc_b2, B1, N, 1);
    gemm_kernel<64, 64, 1, false><<<N / 64, 256, 0, stream>>>(B1, enc_W3, nullptr, dinv, bufA, N);
    agg_kernel<<<(N + 15) / 16, 256, 0, stream>>>(bufA, row_ptr, csr, dinv, enc_b3, B1, N, 0);

    // pooling + decoder head
    pool_kernel<<<(NG * 64 + 255) / 256, 256, 0, stream>>>(B1, emb, NG);
    decinit_kernel<<<(NG * 64 + 255) / 256, 256, 0, stream>>>(emb, dec_Wt, dec_bt, dec_W1, tbuf, NG);
    z1_kernel<<<(N * 16 + 255) / 256, 256, 0, stream>>>(tbuf, dec_b1, B1, N);

    // decoder stencil layers
    gemm_kernel<64, 64, 2, false><<<N / 64, 256, 0, stream>>>(B1, dec_W2, nullptr, nullptr, bufA, N);
    stencil_kernel<<<NG, 256, 0, stream>>>(bufA, dec_b2, B1, NG);
    gemm_kernel<64, 64, 2, false><<<N / 64, 256, 0, stream>>>(B1, dec_W3, nullptr, nullptr, B2, N);
    stencil_kernel<<<NG, 256, 0, stream>>>(B2, dec_b3, bufA, NG);

    // output projection (reads ws bufA, overwrites all of d_out)
    gemm_kernel<64, 128, 0, true><<<N / 32, 256, 0, stream>>>(bufA, out_W, out_b, nullptr,
                                                              (float*)d_out, N);
}

// Round 3
// 893.984 us; speedup vs baseline: 1.7171x; 1.1649x over previous
//
#include <hip/hip_runtime.h>
#include <hip/hip_bf16.h>
#include <cstdint>

#define HID 64
#define NPG 100

typedef short bf16x8 __attribute__((ext_vector_type(8)));
typedef float f32x4 __attribute__((ext_vector_type(4)));

__device__ __forceinline__ unsigned short bf16_rn(float f) {
    union { float f; unsigned u; } c; c.f = f;
    unsigned r = c.u + 0x7fffu + ((c.u >> 16) & 1u);
    return (unsigned short)(r >> 16);
}
__device__ __forceinline__ float bf16_f(unsigned short h) {
    union { unsigned u; float f; } c; c.u = ((unsigned)h) << 16;
    return c.f;
}

// decoder chain-graph degree: in-edges into position p come from p-1,p-2,p+1,p+2 (valid ones), +1 self-loop
__device__ __forceinline__ float dinvdec(int p) {
    int d = (p >= 1) + (p >= 2) + (p <= NPG - 2) + (p <= NPG - 3);
    return rsqrtf((float)(d + 1));
}

// ---------------- CSR build ----------------

__global__ void zero_int_kernel(int* __restrict__ p, int n) {
    int i = blockIdx.x * 256 + threadIdx.x;
    if (i < n) p[i] = 0;
}

__global__ void count_kernel(const int* __restrict__ dst, int* __restrict__ cnt, int E) {
    int e = blockIdx.x * 256 + threadIdx.x;
    if (e < E) atomicAdd(&cnt[dst[e]], 1);
}

__global__ void dinv_kernel(const int* __restrict__ cnt, float* __restrict__ dinv, int N) {
    int i = blockIdx.x * 256 + threadIdx.x;
    if (i < N) dinv[i] = rsqrtf((float)cnt[i] + 1.0f);
}

// block scans 2048 ints (256 thr x 8)
__global__ __launch_bounds__(256) void scan1_kernel(const int* __restrict__ cnt,
                                                    int* __restrict__ row_ptr,
                                                    int* __restrict__ partials, int N) {
    __shared__ int sd[256];
    int tid = threadIdx.x;
    int base = blockIdx.x * 2048 + tid * 8;
    int v[8];
    int s = 0;
#pragma unroll
    for (int j = 0; j < 8; j++) {
        int i = base + j;
        int t = (i < N) ? cnt[i] : 0;
        v[j] = t; s += t;
    }
    sd[tid] = s;
    __syncthreads();
    for (int off = 1; off < 256; off <<= 1) {
        int t = (tid >= off) ? sd[tid - off] : 0;
        __syncthreads();
        sd[tid] += t;
        __syncthreads();
    }
    int run = sd[tid] - s;  // exclusive within block
#pragma unroll
    for (int j = 0; j < 8; j++) {
        int i = base + j;
        if (i < N) row_ptr[i] = run;
        run += v[j];
    }
    if (tid == 0) partials[blockIdx.x] = sd[255];
}

__global__ void scan2_kernel(int* __restrict__ partials, int nb) {
    __shared__ int sd[128];
    int tid = threadIdx.x;
    int v = (tid < nb) ? partials[tid] : 0;
    sd[tid] = v;
    __syncthreads();
    for (int off = 1; off < 128; off <<= 1) {
        int t = (tid >= off) ? sd[tid - off] : 0;
        __syncthreads();
        sd[tid] += t;
        __syncthreads();
    }
    if (tid < nb) partials[tid] = sd[tid] - v;
}

__global__ void scan3_kernel(int* __restrict__ row_ptr, const int* __restrict__ partials,
                             int N, int E) {
    int base = blockIdx.x * 2048 + threadIdx.x * 8;
    int add = partials[blockIdx.x];
#pragma unroll
    for (int j = 0; j < 8; j++) {
        int i = base + j;
        if (i < N) row_ptr[i] += add;
    }
    if (blockIdx.x == 0 && threadIdx.x == 0) row_ptr[N] = E;
}

__global__ void fill_kernel(const int* __restrict__ src, const int* __restrict__ dst,
                            const int* __restrict__ row_ptr, int* __restrict__ cursor,
                            int* __restrict__ csr_src, int E) {
    int e = blockIdx.x * 256 + threadIdx.x;
    if (e >= E) return;
    int d = dst[e];
    int pos = row_ptr[d] + atomicAdd(&cursor[d], 1);
    csr_src[pos] = src[e];
}

// ---------------- MFMA GEMM (bf16 hi/lo split, fp32-grade accuracy) ----------------
// out[M,N] = A[M,K]@W[K,N], epilogue scale/bias as before.
// W staged in LDS transposed+split (Wt[plane][n][k], pad +8 -> 2-way-only conflicts).
// A loaded global->regs (lane&15 = row, (lane>>4)*8 = k-slot; same bijection used
// for B frags so MFMA pairing is consistent). Next-strip A prefetched in regs.
template <int K, int N, int SCALE_MODE, bool BIAS>
__global__ __launch_bounds__(256, 2) void mfma_gemm(const float* __restrict__ A,
                                                    const float* __restrict__ W,
                                                    const float* __restrict__ bias,
                                                    const float* __restrict__ rowscale,
                                                    float* __restrict__ out, int M) {
    constexpr int KP = K + 8;
    constexpr int NT = N / 16;
    constexpr int KS = K / 32;
    __shared__ unsigned short Wt[2][N][KP];
    const int tid = threadIdx.x;

    for (int idx = tid; idx < K * N; idx += 256) {
        float w = W[idx];
        int k = idx / N, n = idx % N;  // N is pow2
        unsigned short h = bf16_rn(w);
        Wt[0][n][k] = h;
        Wt[1][n][k] = bf16_rn(w - bf16_f(h));
    }
    __syncthreads();

    const int lane = tid & 63;
    const int l15 = lane & 15;
    const int lg = lane >> 4;  // 0..3
    const int nstrips = M / 16;
    const int wglobal = blockIdx.x * 4 + (tid >> 6);
    const int wtotal = gridDim.x * 4;

    float cur[KS * 8], nxt[KS * 8];

    auto loadA = [&](int s, float* dstv) {
        const float* arow = A + (size_t)(s * 16 + l15) * K + lg * 8;
#pragma unroll
        for (int ks = 0; ks < KS; ks++) {
            float4 a = *(const float4*)(arow + ks * 32);
            float4 b = *(const float4*)(arow + ks * 32 + 4);
            dstv[ks * 8 + 0] = a.x; dstv[ks * 8 + 1] = a.y;
            dstv[ks * 8 + 2] = a.z; dstv[ks * 8 + 3] = a.w;
            dstv[ks * 8 + 4] = b.x; dstv[ks * 8 + 5] = b.y;
            dstv[ks * 8 + 6] = b.z; dstv[ks * 8 + 7] = b.w;
        }
    };

    int s = wglobal;
    if (s < nstrips) loadA(s, cur);
    for (; s < nstrips; s += wtotal) {
        int sn = s + wtotal;
        if (sn < nstrips) loadA(sn, nxt);

        f32x4 acc[NT];
#pragma unroll
        for (int t = 0; t < NT; t++) acc[t] = f32x4{0.f, 0.f, 0.f, 0.f};

#pragma unroll
        for (int ks = 0; ks < KS; ks++) {
            bf16x8 ah, al;
#pragma unroll
            for (int j = 0; j < 8; j++) {
                float v = cur[ks * 8 + j];
                unsigned short h = bf16_rn(v);
                ah[j] = (short)h;
                al[j] = (short)bf16_rn(v - bf16_f(h));
            }
            const int k0 = ks * 32 + lg * 8;
#pragma unroll
            for (int t = 0; t < NT; t++) {
                int n = t * 16 + l15;
                bf16x8 bh = *(const bf16x8*)&Wt[0][n][k0];
                bf16x8 bl = *(const bf16x8*)&Wt[1][n][k0];
                acc[t] = __builtin_amdgcn_mfma_f32_16x16x32_bf16(ah, bh, acc[t], 0, 0, 0);
                acc[t] = __builtin_amdgcn_mfma_f32_16x16x32_bf16(ah, bl, acc[t], 0, 0, 0);
                acc[t] = __builtin_amdgcn_mfma_f32_16x16x32_bf16(al, bh, acc[t], 0, 0, 0);
            }
        }

#pragma unroll
        for (int r = 0; r < 4; r++) {
            int row = s * 16 + lg * 4 + r;
            float scale = 1.0f;
            if (SCALE_MODE == 1) scale = rowscale[row];
            if (SCALE_MODE == 2) scale = dinvdec(row % NPG);
#pragma unroll
            for (int t = 0; t < NT; t++) {
                float o = acc[t][r] * scale;
                if (BIAS) o += bias[t * 16 + l15];
                out[(size_t)row * N + t * 16 + l15] = o;
            }
        }
#pragma unroll
        for (int i = 0; i < KS * 8; i++) cur[i] = nxt[i];
    }
}

// ---------------- encoder aggregation (gather over CSR) ----------------
// 16 lanes/row (float4/lane = 256B/gather); 16-deep index+gather pipeline.
__global__ __launch_bounds__(256) void agg_kernel(const float* __restrict__ g,
                                                  const int* __restrict__ row_ptr,
                                                  const int* __restrict__ csr_src,
                                                  const float* __restrict__ dinv,
                                                  const float* __restrict__ bias,
                                                  float* __restrict__ out, int N, int do_relu) {
    const int tid = threadIdx.x;
    const int sub = tid >> 4;
    const int lg = tid & 15;
    const int row = blockIdx.x * 16 + sub;
    if (row >= N) return;

    const float4* g4 = (const float4*)g;
    float4 acc = g4[(size_t)row * 16 + lg];

    const int s = row_ptr[row];
    const int e = row_ptr[row + 1];
    int j = s;

#define ACC4(vv) do { acc.x += vv.x; acc.y += vv.y; acc.z += vv.z; acc.w += vv.w; } while (0)

    for (; j + 16 <= e; j += 16) {
        int idx[16];
#pragma unroll
        for (int t = 0; t < 16; t++) idx[t] = csr_src[j + t];
        float4 v[16];
#pragma unroll
        for (int t = 0; t < 16; t++) v[t] = g4[(size_t)idx[t] * 16 + lg];
#pragma unroll
        for (int t = 0; t < 16; t++) ACC4(v[t]);
    }
    for (; j + 8 <= e; j += 8) {
        int idx[8];
#pragma unroll
        for (int t = 0; t < 8; t++) idx[t] = csr_src[j + t];
        float4 v[8];
#pragma unroll
        for (int t = 0; t < 8; t++) v[t] = g4[(size_t)idx[t] * 16 + lg];
#pragma unroll
        for (int t = 0; t < 8; t++) ACC4(v[t]);
    }
    for (; j + 2 <= e; j += 2) {
        int i0 = csr_src[j + 0], i1 = csr_src[j + 1];
        float4 v0 = g4[(size_t)i0 * 16 + lg];
        float4 v1 = g4[(size_t)i1 * 16 + lg];
        ACC4(v0); ACC4(v1);
    }
    if (j < e) {
        int i0 = csr_src[j];
        float4 v0 = g4[(size_t)i0 * 16 + lg];
        ACC4(v0);
    }
#undef ACC4

    const float d = dinv[row];
    float4 bv = ((const float4*)bias)[lg];
    float4 o;
    o.x = d * acc.x + bv.x;
    o.y = d * acc.y + bv.y;
    o.z = d * acc.z + bv.z;
    o.w = d * acc.w + bv.w;
    if (do_relu) {
        o.x = fmaxf(o.x, 0.0f); o.y = fmaxf(o.y, 0.0f);
        o.z = fmaxf(o.z, 0.0f); o.w = fmaxf(o.w, 0.0f);
    }
    ((float4*)out)[(size_t)row * 16 + lg] = o;
}

// ---------------- pooling: mean over each graph's 100 rows ----------------
__global__ void pool_kernel(const float* __restrict__ h, float* __restrict__ emb, int NG) {
    int wid = (blockIdx.x * 256 + threadIdx.x) >> 6;
    int lane = threadIdx.x & 63;
    if (wid >= NG) return;
    const float* base = h + (size_t)wid * NPG * HID + lane;
    float acc = 0.0f;
    for (int i = 0; i < NPG; i++) acc += base[i * HID];
    emb[wid * HID + lane] = acc * (1.0f / NPG);
}

// ---------------- decoder init: t = (emb@Wt + bt) @ W1, one wave per graph ----------------
__global__ void decinit_kernel(const float* __restrict__ emb, const float* __restrict__ Wt,
                               const float* __restrict__ bt, const float* __restrict__ W1,
                               float* __restrict__ t, int NG) {
    int wid = (blockIdx.x * 256 + threadIdx.x) >> 6;
    int lane = threadIdx.x & 63;
    if (wid >= NG) return;
    float e = emb[wid * HID + lane];
    float acc = bt[lane];
    for (int k = 0; k < HID; k++) acc += __shfl(e, k) * Wt[k * HID + lane];
    float tv = 0.0f;
    for (int k = 0; k < HID; k++) tv += __shfl(acc, k) * W1[k * HID + lane];
    t[wid * HID + lane] = tv;
}

// ---------------- decoder layer 1: z1[i] = relu(t[graph]*s[pos] + b1) ----------------
__global__ void z1_kernel(const float* __restrict__ t, const float* __restrict__ b1,
                          float* __restrict__ out, int N) {
    int i4 = blockIdx.x * 256 + threadIdx.x;
    if (i4 >= N * (HID / 4)) return;
    int row = i4 >> 4, c4 = i4 & 15;
    int gph = row / NPG;
    int p = row - gph * NPG;
    float dp = dinvdec(p);
    float qs = dp;
    if (p >= 1) qs += dinvdec(p - 1);
    if (p >= 2) qs += dinvdec(p - 2);
    if (p <= NPG - 2) qs += dinvdec(p + 1);
    if (p <= NPG - 3) qs += dinvdec(p + 2);
    float s = dp * qs;
    float4 tv = ((const float4*)t)[gph * (HID / 4) + c4];
    float4 bv = ((const float4*)b1)[c4];
    float4 o;
    o.x = fmaxf(s * tv.x + bv.x, 0.0f);
    o.y = fmaxf(s * tv.y + bv.y, 0.0f);
    o.z = fmaxf(s * tv.z + bv.z, 0.0f);
    o.w = fmaxf(s * tv.w + bv.w, 0.0f);
    ((float4*)out)[i4] = o;
}

// ---------------- decoder stencil layers (one block per graph) ----------------
__global__ __launch_bounds__(256) void stencil_kernel(const float* __restrict__ g,
                                                      const float* __restrict__ bias,
                                                      float* __restrict__ out, int NG) {
    __shared__ float gs[NPG * HID];
    int gph = blockIdx.x;
    const float4* src = (const float4*)(g + (size_t)gph * NPG * HID);
    for (int idx = threadIdx.x; idx < NPG * HID / 4; idx += 256)
        ((float4*)gs)[idx] = src[idx];
    __syncthreads();
    int c = threadIdx.x & 63;
    for (int p = threadIdx.x >> 6; p < NPG; p += 4) {
        float acc = gs[p * HID + c];
        if (p >= 1) acc += gs[(p - 1) * HID + c];
        if (p >= 2) acc += gs[(p - 2) * HID + c];
        if (p <= NPG - 2) acc += gs[(p + 1) * HID + c];
        if (p <= NPG - 3) acc += gs[(p + 2) * HID + c];
        float v = dinvdec(p) * acc + bias[c];
        v = fmaxf(v, 0.0f);
        out[(size_t)(gph * NPG + p) * HID + c] = v;
    }
}

// ---------------- launch ----------------

extern "C" void kernel_launch(void* const* d_in, const int* in_sizes, int n_in,
                              void* d_out, int out_size, void* d_ws, size_t ws_size,
                              hipStream_t stream) {
    const float* x      = (const float*)d_in[0];
    const int*   edge   = (const int*)d_in[1];
    const float* enc_W1 = (const float*)d_in[3];
    const float* enc_b1 = (const float*)d_in[4];
    const float* enc_W2 = (const float*)d_in[5];
    const float* enc_b2 = (const float*)d_in[6];
    const float* enc_W3 = (const float*)d_in[7];
    const float* enc_b3 = (const float*)d_in[8];
    const float* dec_Wt = (const float*)d_in[9];
    const float* dec_bt = (const float*)d_in[10];
    const float* dec_W1 = (const float*)d_in[11];
    const float* dec_b1 = (const float*)d_in[12];
    const float* dec_W2 = (const float*)d_in[13];
    const float* dec_b2 = (const float*)d_in[14];
    const float* dec_W3 = (const float*)d_in[15];
    const float* dec_b3 = (const float*)d_in[16];
    const float* out_W  = (const float*)d_in[17];
    const float* out_b  = (const float*)d_in[18];

    const int N  = in_sizes[0] / 128;  // 200000
    const int E  = in_sizes[1] / 2;    // 3200000
    const int NG = N / NPG;            // 2000
    const int* esrc = edge;
    const int* edst = edge + E;

    char* w = (char*)d_ws;
    auto alloc = [&](size_t bytes) -> void* {
        void* p = (void*)w;
        w += (bytes + 255) & ~(size_t)255;
        return p;
    };
    float* bufA    = (float*)alloc((size_t)N * HID * 4);
    int*   csr     = (int*)alloc((size_t)E * 4);
    int*   row_ptr = (int*)alloc((size_t)(N + 1) * 4);
    int*   cnt     = (int*)alloc((size_t)N * 4);
    int*   cursor  = (int*)alloc((size_t)N * 4);
    float* dinv    = (float*)alloc((size_t)N * 4);
    int*   partials= (int*)alloc(1024);
    float* emb     = (float*)alloc((size_t)NG * HID * 4);
    float* tbuf    = (float*)alloc((size_t)NG * HID * 4);

    float* B1 = (float*)d_out;                    // first half of d_out as scratch
    float* B2 = (float*)d_out + (size_t)N * HID;  // second half

    const int NB = (N + 2047) / 2048;
    const int GB = 1024;  // gemm blocks (4 waves each)

    // CSR build
    zero_int_kernel<<<(N + 255) / 256, 256, 0, stream>>>(cnt, N);
    zero_int_kernel<<<(N + 255) / 256, 256, 0, stream>>>(cursor, N);
    count_kernel<<<(E + 255) / 256, 256, 0, stream>>>(edst, cnt, E);
    dinv_kernel<<<(N + 255) / 256, 256, 0, stream>>>(cnt, dinv, N);
    scan1_kernel<<<NB, 256, 0, stream>>>(cnt, row_ptr, partials, N);
    scan2_kernel<<<1, 128, 0, stream>>>(partials, NB);
    scan3_kernel<<<NB, 256, 0, stream>>>(row_ptr, partials, N, E);
    fill_kernel<<<(E + 255) / 256, 256, 0, stream>>>(esrc, edst, row_ptr, cursor, csr, E);

    // encoder
    mfma_gemm<128, 64, 1, false><<<GB, 256, 0, stream>>>(x, enc_W1, nullptr, dinv, bufA, N);
    agg_kernel<<<(N + 15) / 16, 256, 0, stream>>>(bufA, row_ptr, csr, dinv, enc_b1, B1, N, 1);
    mfma_gemm<64, 64, 1, false><<<GB, 256, 0, stream>>>(B1, enc_W2, nullptr, dinv, bufA, N);
    agg_kernel<<<(N + 15) / 16, 256, 0, stream>>>(bufA, row_ptr, csr, dinv, enc_b2, B1, N, 1);
    mfma_gemm<64, 64, 1, false><<<GB, 256, 0, stream>>>(B1, enc_W3, nullptr, dinv, bufA, N);
    agg_kernel<<<(N + 15) / 16, 256, 0, stream>>>(bufA, row_ptr, csr, dinv, enc_b3, B1, N, 0);

    // pooling + decoder head
    pool_kernel<<<(NG * 64 + 255) / 256, 256, 0, stream>>>(B1, emb, NG);
    decinit_kernel<<<(NG * 64 + 255) / 256, 256, 0, stream>>>(emb, dec_Wt, dec_bt, dec_W1, tbuf, NG);
    z1_kernel<<<(N * 16 + 255) / 256, 256, 0, stream>>>(tbuf, dec_b1, B1, N);

    // decoder stencil layers
    mfma_gemm<64, 64, 2, false><<<GB, 256, 0, stream>>>(B1, dec_W2, nullptr, nullptr, bufA, N);
    stencil_kernel<<<NG, 256, 0, stream>>>(bufA, dec_b2, B1, NG);
    mfma_gemm<64, 64, 2, false><<<GB, 256, 0, stream>>>(B1, dec_W3, nullptr, nullptr, B2, N);
    stencil_kernel<<<NG, 256, 0, stream>>>(B2, dec_b3, bufA, NG);

    // output projection
    mfma_gemm<64, 128, 0, true><<<GB, 256, 0, stream>>>(bufA, out_W, out_b, nullptr,
                                                        (float*)d_out, N);
}